// Round 1
// 93.551 us; speedup vs baseline: 1.0277x; 1.0277x over previous
//
#include <hip/hip_runtime.h>

// CrAKNVectorAttention: softmax over j sums to 1, so
//   out[i,k] = v[i,k] * sum_j softmax_j(h)[i,j,k] = v[i,k] = (feat @ Wv + bv)[i,k].
// The whole module collapses to one N x C x C f32 bias-GEMM.
//
// R3 theory: measured 96 us is dominated by harness ws-poison fills (2x ~40 us,
// 268 MB @ 84% HBM peak, top-5 dispatches) which we cannot touch. The kernel's
// own share (~8-16 us) was L2-LATENCY-bound: grid 256 x block 256 = 1 wave/SIMD,
// 256 serial-ish Wv dword loads (~250 cyc L2 hit each, unroll-8 in flight) with
// no co-resident wave to hide the wait. VALU floor is only ~0.85 us.
//
// Fix: in-block split-K. 1024-thread blocks (still 256 blocks = 1/CU), wave-
// uniform ks = tid>>8 takes a disjoint 64-wide K-slice; c = tid&255 keeps the
// coalesced Wv column load and scalarized (wave-uniform) feat reads. 16 waves/CU
// (4/SIMD) overlap loads with FMAs; partials reduce via 12 KB LDS (stride-1,
// conflict-free). Wv L2 traffic unchanged at 64 MB. VGPR < 128 so all 16 waves
// resident (__launch_bounds__(1024,4)).
//
// Inputs (f32): d_in[0]=feat [N,C], d_in[9]=Wv [C,C], d_in[10]=bv [C].
// Output: f32 [N,C].

#define NN 1024
#define CC 256
#define TM 4            // rows per block
#define KS 4            // K-slices per block (one per 4-wave group)
#define KL (CC / KS)    // 64 k's per slice

__global__ __launch_bounds__(1024, 4) void v_bias_gemm_splitk(
    const float* __restrict__ feat,
    const float* __restrict__ Wv,
    const float* __restrict__ bv,
    float* __restrict__ out)
{
    __shared__ float red[KS - 1][TM][CC];   // 12 KB, partials from slices 1..3

    const int c  = threadIdx.x & (CC - 1);  // output column 0..255
    const int ks = threadIdx.x >> 8;        // K-slice 0..3, wave-uniform
    const int row0 = blockIdx.x * TM;

    // wave-uniform base -> compiler scalarizes feat reads to s_load (K$)
    const float* __restrict__ f0 = feat + row0 * CC + ks * KL;
    // coalesced column loads: lane c reads Wv[k][c], 256 B per wave per k
    const float* __restrict__ wv = Wv + ks * KL * CC + c;

    float a0 = 0.f, a1 = 0.f, a2 = 0.f, a3 = 0.f;

    #pragma unroll 16
    for (int k = 0; k < KL; ++k) {
        const float w = wv[k * CC];
        a0 = fmaf(f0[0 * CC + k], w, a0);
        a1 = fmaf(f0[1 * CC + k], w, a1);
        a2 = fmaf(f0[2 * CC + k], w, a2);
        a3 = fmaf(f0[3 * CC + k], w, a3);
    }

    if (ks != 0) {
        red[ks - 1][0][c] = a0;
        red[ks - 1][1][c] = a1;
        red[ks - 1][2][c] = a2;
        red[ks - 1][3][c] = a3;
    }
    __syncthreads();

    if (ks == 0) {
        const float b = bv[c];
        a0 += red[0][0][c] + red[1][0][c] + red[2][0][c];
        a1 += red[0][1][c] + red[1][1][c] + red[2][1][c];
        a2 += red[0][2][c] + red[1][2][c] + red[2][2][c];
        a3 += red[0][3][c] + red[1][3][c] + red[2][3][c];
        out[(row0 + 0) * CC + c] = a0 + b;
        out[(row0 + 1) * CC + c] = a1 + b;
        out[(row0 + 2) * CC + c] = a2 + b;
        out[(row0 + 3) * CC + c] = a3 + b;
    }
}

extern "C" void kernel_launch(void* const* d_in, const int* in_sizes, int n_in,
                              void* d_out, int out_size, void* d_ws, size_t ws_size,
                              hipStream_t stream) {
    (void)in_sizes; (void)n_in; (void)d_ws; (void)ws_size; (void)out_size;
    const float* feat = (const float*)d_in[0];
    const float* Wv   = (const float*)d_in[9];
    const float* bv   = (const float*)d_in[10];
    float* out = (float*)d_out;

    dim3 grid(NN / TM);     // 256 blocks -> 1 per CU
    dim3 block(KS * CC);    // 1024 threads = 16 waves
    v_bias_gemm_splitk<<<grid, block, 0, stream>>>(feat, Wv, bv, out);
}

// Round 2
// 85.394 us; speedup vs baseline: 1.1259x; 1.0955x over previous
//
#include <hip/hip_runtime.h>

// CrAKNVectorAttention: softmax over j sums to 1, so
//   out[i,k] = v[i,k] * sum_j softmax_j(h)[i,j,k] = v[i,k] = (feat @ Wv + bv)[i,k].
// The whole module collapses to one N x C x C f32 bias-GEMM.
//
// R4 theory: harness poison fills (2 x ~40 us, 268 MB @ 84% HBM peak) are the
// measured floor; kernel residual ~13 us. R1's kernel was VMEM-ISSUE bound:
// ks = tid>>8 is "divergent" to AMDGPU uniformity analysis, so the 4 feat reads
// per k were vector loads, not s_loads -> (1 Wv + 4 feat) x 64 k = 320 VMEM
// wave-instrs vs 256 FMA wave-cycles.
//
// Fix: (a) float4 Wv columns + 16-way split-K: 16 dwordx4 loads/thread (4x fewer
// VMEM instrs, same bytes, 16 outstanding 1KB loads/wave for latency hiding);
// (b) readfirstlane(ks) makes the feat address provably wave-uniform again ->
// s_load_dwordx16 (4/wave, feat values feed FMAs as SGPR operands);
// (c) reduce via 64 KB LDS, 1 barrier, 1 output elem per thread (16 stride-1
// ds_reads, conflict-free), coalesced stores.
//
// Inputs (f32): d_in[0]=feat [N,C], d_in[9]=Wv [C,C], d_in[10]=bv [C].
// Output: f32 [N,C].

#define NN 1024
#define CC 256
#define TM 4            // rows per block: 256 blocks -> 1/CU
#define KS 16           // K-slices = waves per block
#define KL (CC / KS)    // 16 k's per slice

__global__ __launch_bounds__(1024, 4) void v_bias_gemm_splitk16(
    const float* __restrict__ feat,
    const float* __restrict__ Wv,
    const float* __restrict__ bv,
    float* __restrict__ out)
{
    __shared__ float red[KS][TM][CC];       // 64 KB partials

    const int tid  = threadIdx.x;
    const int lane = tid & 63;
    const int c4   = lane * 4;              // 4 consecutive output columns
    // wave id = K-slice; readfirstlane makes it SGPR (exact: uniform per wave)
    const int ks   = __builtin_amdgcn_readfirstlane(tid >> 6);
    const int row0 = blockIdx.x * TM;

    // uniform base -> s_load_dwordx16 per row slice (64 B contiguous)
    const float* __restrict__ f0 = feat + row0 * CC + ks * KL;
    // coalesced: wave reads Wv[k][0..255] as 64 x float4 = 1 KB per k
    const float* __restrict__ wv = Wv + (ks * KL) * CC + c4;

    float4 a0 = {0.f, 0.f, 0.f, 0.f};
    float4 a1 = a0, a2 = a0, a3 = a0;

    #pragma unroll
    for (int k = 0; k < KL; ++k) {
        const float4 w = *(const float4*)(wv + k * CC);
        const float s0 = f0[0 * CC + k];
        const float s1 = f0[1 * CC + k];
        const float s2 = f0[2 * CC + k];
        const float s3 = f0[3 * CC + k];
        a0.x = fmaf(s0, w.x, a0.x); a0.y = fmaf(s0, w.y, a0.y);
        a0.z = fmaf(s0, w.z, a0.z); a0.w = fmaf(s0, w.w, a0.w);
        a1.x = fmaf(s1, w.x, a1.x); a1.y = fmaf(s1, w.y, a1.y);
        a1.z = fmaf(s1, w.z, a1.z); a1.w = fmaf(s1, w.w, a1.w);
        a2.x = fmaf(s2, w.x, a2.x); a2.y = fmaf(s2, w.y, a2.y);
        a2.z = fmaf(s2, w.z, a2.z); a2.w = fmaf(s2, w.w, a2.w);
        a3.x = fmaf(s3, w.x, a3.x); a3.y = fmaf(s3, w.y, a3.y);
        a3.z = fmaf(s3, w.z, a3.z); a3.w = fmaf(s3, w.w, a3.w);
    }

    // partials -> LDS (float4, lane-stride 16 B: standard conflict-free pattern)
    *(float4*)&red[ks][0][c4] = a0;
    *(float4*)&red[ks][1][c4] = a1;
    *(float4*)&red[ks][2][c4] = a2;
    *(float4*)&red[ks][3][c4] = a3;
    __syncthreads();

    // one output element per thread: 1024 threads = TM x CC outputs
    const int r = tid >> 8;                 // 0..3
    const int c = tid & (CC - 1);           // 0..255, lane-stride 4 B ds_reads
    float s = red[0][r][c];
    #pragma unroll
    for (int ss = 1; ss < KS; ++ss) s += red[ss][r][c];
    out[(row0 + r) * CC + c] = s + bv[c];   // coalesced 256 B/wave
}

extern "C" void kernel_launch(void* const* d_in, const int* in_sizes, int n_in,
                              void* d_out, int out_size, void* d_ws, size_t ws_size,
                              hipStream_t stream) {
    (void)in_sizes; (void)n_in; (void)d_ws; (void)ws_size; (void)out_size;
    const float* feat = (const float*)d_in[0];
    const float* Wv   = (const float*)d_in[9];
    const float* bv   = (const float*)d_in[10];
    float* out = (float*)d_out;

    dim3 grid(NN / TM);     // 256 blocks -> 1 per CU
    dim3 block(KS * 64);    // 1024 threads = 16 waves
    v_bias_gemm_splitk16<<<grid, block, 0, stream>>>(feat, Wv, bv, out);
}